// Round 1
// 369.515 us; speedup vs baseline: 1.0625x; 1.0625x over previous
//
#include <hip/hip_runtime.h>
#include <hip/hip_bf16.h>
#include <stdint.h>
#include <stddef.h>

// Problem constants (fixed by the reference)
#define B_DIM 4
#define NH    16
#define LSEQ  2048
#define HD    64
#define DM    1024
#define TOKENS (B_DIM * LSEQ)   // 8192

typedef __bf16 bf16_t;
typedef __attribute__((ext_vector_type(8))) __bf16 bf16x8;
typedef __attribute__((ext_vector_type(4))) __bf16 bf16x4;
typedef __attribute__((ext_vector_type(4))) float  f32x4;

// async global->LDS, 16B per lane, lane i lands at ldsbase + i*16
#define GLD16(gp, lp) \
  __builtin_amdgcn_global_load_lds((__attribute__((address_space(1))) void*)(gp), \
                                   (__attribute__((address_space(3))) void*)(lp), 16, 0, 0)

__device__ __forceinline__ f32x4 mfma_16x16x32(bf16x8 a, bf16x8 b, f32x4 c) {
  return __builtin_amdgcn_mfma_f32_16x16x32_bf16(a, b, c, 0, 0, 0);
}

// ---------------------------------------------------------------------------
// Casts: 3 activations (dst contiguous: xq,xk,xv) / 4 weights (wq,wk,wv,wo)
// ---------------------------------------------------------------------------
__global__ __launch_bounds__(256) void cast3_kernel(const float* __restrict__ a,
                                                    const float* __restrict__ b,
                                                    const float* __restrict__ c,
                                                    bf16_t* __restrict__ dst, int n) {
  const float* src = (blockIdx.y == 0) ? a : (blockIdx.y == 1) ? b : c;
  const int i = (blockIdx.x * 256 + threadIdx.x) * 4;
  if (i < n) {
    const float4 v = *(const float4*)(src + i);
    bf16x4 o;
    o[0] = (bf16_t)v.x; o[1] = (bf16_t)v.y; o[2] = (bf16_t)v.z; o[3] = (bf16_t)v.w;
    *(bf16x4*)(dst + (size_t)blockIdx.y * n + i) = o;
  }
}

__global__ __launch_bounds__(256) void cast4_kernel(const float* __restrict__ a,
                                                    const float* __restrict__ b,
                                                    const float* __restrict__ c,
                                                    const float* __restrict__ d,
                                                    bf16_t* __restrict__ dst, int n) {
  const float* src = (blockIdx.y == 0) ? a : (blockIdx.y == 1) ? b
                   : (blockIdx.y == 2) ? c : d;
  const int i = (blockIdx.x * 256 + threadIdx.x) * 4;
  if (i < n) {
    const float4 v = *(const float4*)(src + i);
    bf16x4 o;
    o[0] = (bf16_t)v.x; o[1] = (bf16_t)v.y; o[2] = (bf16_t)v.z; o[3] = (bf16_t)v.w;
    *(bf16x4*)(dst + (size_t)blockIdx.y * n + i) = o;
  }
}

// ---------------------------------------------------------------------------
// Fused QKV projection: ONE dispatch, blockIdx.z in {0,1,2} = q,k,v.
// 128x128-tile bf16 GEMM (m97 structure): C = X_z * W_z^T + bias_z, then:
//   z<2 : RoPE epilogue -> head-split [B,NH,LSEQ,HD]
//   z==2: transposed store -> [B,NH,HD,LSEQ] (PV B-operand contiguity)
// ---------------------------------------------------------------------------
__global__ __launch_bounds__(256) void qkv_proj_kernel(const bf16_t* __restrict__ X,
                                                       const bf16_t* __restrict__ Wb,
                                                       const float* __restrict__ bq,
                                                       const float* __restrict__ bk,
                                                       const float* __restrict__ bv,
                                                       const float* __restrict__ cos_q,
                                                       const float* __restrict__ sin_q,
                                                       const float* __restrict__ cos_k,
                                                       const float* __restrict__ sin_k,
                                                       bf16_t* __restrict__ qtb,
                                                       bf16_t* __restrict__ ktb,
                                                       bf16_t* __restrict__ vtb) {
  __shared__ bf16_t As[128 * 32];
  __shared__ bf16_t Bs[128 * 32];
  const int z = blockIdx.z;
  const bf16_t* A  = X  + (size_t)z * TOKENS * DM;
  const bf16_t* Bw = Wb + (size_t)z * DM * DM;
  const float* bias = (z == 0) ? bq : (z == 1) ? bk : bv;

  const int tid  = threadIdx.x;
  const int wave = tid >> 6, lane = tid & 63;
  const int quad = lane >> 4, l16 = lane & 15;
  const int m0 = blockIdx.x * 128, n0 = blockIdx.y * 128;
  const int wm = (wave >> 1) * 64, wn = (wave & 1) * 64;

  f32x4 acc[4][4];
#pragma unroll
  for (int i = 0; i < 4; ++i)
#pragma unroll
    for (int j = 0; j < 4; ++j) acc[i][j] = (f32x4){0.f, 0.f, 0.f, 0.f};

  const int srow = lane >> 2;        // 0..15 (row within 16-row chunk)
  const int scol = (lane & 3) * 8;   // 0,8,16,24

  for (int kk = 0; kk < DM; kk += 32) {
    __syncthreads();
#pragma unroll
    for (int t = 0; t < 2; ++t) {
      const int c   = wave * 2 + t;        // chunk 0..7, 16 rows each
      const int row = c * 16 + srow;
      GLD16(A  + (size_t)(m0 + row) * DM + kk + scol, As + c * 512);
      GLD16(Bw + (size_t)(n0 + row) * DM + kk + scol, Bs + c * 512);
    }
    __syncthreads();
    bf16x8 af[4], bfr[4];
#pragma unroll
    for (int i = 0; i < 4; ++i)
      af[i] = *(const bf16x8*)(As + (wm + i * 16 + l16) * 32 + quad * 8);
#pragma unroll
    for (int j = 0; j < 4; ++j)
      bfr[j] = *(const bf16x8*)(Bs + (wn + j * 16 + l16) * 32 + quad * 8);
#pragma unroll
    for (int i = 0; i < 4; ++i)
#pragma unroll
      for (int j = 0; j < 4; ++j)
        acc[i][j] = mfma_16x16x32(af[i], bfr[j], acc[i][j]);
  }

  // epilogue: C row = quad*4+reg, col = l16 (m89-verified C/D layout)
  if (z < 2) {
    const float* cosb = (z == 0) ? cos_q : cos_k;
    const float* sinb = (z == 0) ? sin_q : sin_k;
    bf16_t* out = (z == 0) ? qtb : ktb;
    const int h = (n0 + wn) >> 6;
#pragma unroll
    for (int i = 0; i < 4; ++i) {
#pragma unroll
      for (int j = 0; j < 2; ++j) {
        const int hd1 = j * 16 + l16;
        const int hd2 = hd1 + 32;
        const float bn1 = bias[n0 + wn + hd1];
        const float bn2 = bias[n0 + wn + hd2];
#pragma unroll
        for (int r = 0; r < 4; ++r) {
          const int m = m0 + wm + i * 16 + quad * 4 + r;
          const int b = m >> 11, l = m & (LSEQ - 1);
          const size_t cb = ((size_t)b * LSEQ + l) * HD;
          const float x1 = (float)(bf16_t)(acc[i][j][r] + bn1);
          const float x2 = (float)(bf16_t)(acc[i][j + 2][r] + bn2);
          const float c1 = cosb[cb + hd1], s1 = sinb[cb + hd1];
          const float c2 = cosb[cb + hd2], s2 = sinb[cb + hd2];
          bf16_t* dst = out + (((size_t)(b * NH + h)) * LSEQ + l) * HD;
          dst[hd1] = (bf16_t)(x1 * c1 - x2 * s1);
          dst[hd2] = (bf16_t)(x2 * c2 + x1 * s2);
        }
      }
    }
  } else {
#pragma unroll
    for (int i = 0; i < 4; ++i) {
      const int mb = m0 + wm + i * 16 + quad * 4;
      const int b = mb >> 11, l = mb & (LSEQ - 1);
#pragma unroll
      for (int j = 0; j < 4; ++j) {
        const int n = n0 + wn + j * 16 + l16;
        const int h = n >> 6, hd = n & (HD - 1);
        const float bn = bias[n];
        bf16x4 pk;
#pragma unroll
        for (int r = 0; r < 4; ++r) pk[r] = (bf16_t)(acc[i][j][r] + bn);
        *(bf16x4*)(vtb + (((size_t)(b * NH + h)) * HD + hd) * LSEQ + l) = pk;
      }
    }
  }
}

// ---------------------------------------------------------------------------
// Out projection: C = A * Wo^T + bo, f32 store (m97 structure)
// ---------------------------------------------------------------------------
__global__ __launch_bounds__(256) void out_gemm_kernel(const bf16_t* __restrict__ A,
                                                       const bf16_t* __restrict__ Bw,
                                                       const float* __restrict__ bias,
                                                       float* __restrict__ out) {
  __shared__ bf16_t As[128 * 32];
  __shared__ bf16_t Bs[128 * 32];
  const int tid  = threadIdx.x;
  const int wave = tid >> 6, lane = tid & 63;
  const int quad = lane >> 4, l16 = lane & 15;
  const int m0 = blockIdx.x * 128, n0 = blockIdx.y * 128;
  const int wm = (wave >> 1) * 64, wn = (wave & 1) * 64;

  f32x4 acc[4][4];
#pragma unroll
  for (int i = 0; i < 4; ++i)
#pragma unroll
    for (int j = 0; j < 4; ++j) acc[i][j] = (f32x4){0.f, 0.f, 0.f, 0.f};

  const int srow = lane >> 2;
  const int scol = (lane & 3) * 8;

  for (int kk = 0; kk < DM; kk += 32) {
    __syncthreads();
#pragma unroll
    for (int t = 0; t < 2; ++t) {
      const int c   = wave * 2 + t;
      const int row = c * 16 + srow;
      GLD16(A  + (size_t)(m0 + row) * DM + kk + scol, As + c * 512);
      GLD16(Bw + (size_t)(n0 + row) * DM + kk + scol, Bs + c * 512);
    }
    __syncthreads();
    bf16x8 af[4], bfr[4];
#pragma unroll
    for (int i = 0; i < 4; ++i)
      af[i] = *(const bf16x8*)(As + (wm + i * 16 + l16) * 32 + quad * 8);
#pragma unroll
    for (int j = 0; j < 4; ++j)
      bfr[j] = *(const bf16x8*)(Bs + (wn + j * 16 + l16) * 32 + quad * 8);
#pragma unroll
    for (int i = 0; i < 4; ++i)
#pragma unroll
      for (int j = 0; j < 4; ++j)
        acc[i][j] = mfma_16x16x32(af[i], bfr[j], acc[i][j]);
  }

#pragma unroll
  for (int i = 0; i < 4; ++i)
#pragma unroll
    for (int j = 0; j < 4; ++j) {
      const int n  = n0 + wn + j * 16 + l16;
      const float bn = bias[n];
#pragma unroll
      for (int r = 0; r < 4; ++r) {
        const int m = m0 + wm + i * 16 + quad * 4 + r;
        out[(size_t)m * DM + n] = acc[i][j][r] + bn;
      }
    }
}

// ---------------------------------------------------------------------------
// Flash attention v5: grid (LSEQ/128, B*NH), 256 threads (4 waves x 32 q-rows).
// Round-5 changes (latency-bound fix, counters: MfmaUtil 24 / VALU 45 / occ 36,
// nothing saturated -> single-buffer stage stall was the serial term):
//  - SWAPPED QK^T (mfma(K,Q)): lane holds q=l16, positions p=j*16+quad*4+r.
//  - K rows sigma-PERMUTED at stage time, sigma(p)={p5,p3,p2,p4,p1,p0}, so the
//    static re-gather pa[f][e] = (bf16)S[2f+(e>>2)][e&3] puts original-k slot
//    s = f*32+quad*8+e in the PV A-operand: P transpose fully IN-REGISTER.
//    Deletes the Pl slab (9.2 KB LDS, 32 ds_write_b16 + 4 ds_read_b128/iter).
//    P/O bit-identical to v4; V path untouched.
//  - mask under sigma = two contiguous 8B chunks/lane; __all fast path.
//  - DOUBLE-BUFFERED K/V (2x16 KB = 32 KB LDS, still >=4 blocks/CU = grid cap,
//    so no round-4 occupancy cliff): T3-minimum 2-phase, prefetch next tile
//    before compute, ONE __syncthreads per tile (its implicit vmcnt(0) drain
//    covers the prefetch). Stage latency hides under MFMA+exp2.
//  - l reduction via shfl tree (xor 16,32) + shfl redistribute: no LDS, no bar.
// ---------------------------------------------------------------------------
__global__ __launch_bounds__(256, 4) void attn_kernel(const bf16_t* __restrict__ qt,
                                                      const bf16_t* __restrict__ kt,
                                                      const bf16_t* __restrict__ vt,
                                                      const unsigned char* __restrict__ mask,
                                                      bf16_t* __restrict__ ctx) {
  __shared__ bf16_t Kl[2][64 * 64];        // [pos][d], col-blocks swizzled by pos&7
  __shared__ bf16_t Vl[2][64 * 64];        // [d][kk],  col-blocks swizzled by d&7
  const int bh = blockIdx.y;
  const int b = bh >> 4, h = bh & (NH - 1);
  const int q0 = blockIdx.x * 128;
  const int tid = threadIdx.x;
  const int wave = tid >> 6, lane = tid & 63;
  const int quad = lane >> 4, l16 = lane & 15;
  const float scale_l2e = 0.125f * 1.44269504f;  // HD^-0.5 * log2(e)

  // Q fragments (m=l16, k=quad*8+e), used as B-operand of swapped QK^T
  bf16x8 qa[2][2];
#pragma unroll
  for (int u = 0; u < 2; ++u) {
    const bf16_t* qrow = qt + (((size_t)bh * LSEQ) + q0 + wave * 32 + u * 16 + l16) * HD;
    qa[u][0] = *(const bf16x8*)(qrow + quad * 8);
    qa[u][1] = *(const bf16x8*)(qrow + 32 + quad * 8);
  }

  f32x4 O[2][4];
  float l_part[2] = {0.f, 0.f};
#pragma unroll
  for (int u = 0; u < 2; ++u)
#pragma unroll
    for (int j = 0; j < 4; ++j) O[u][j] = (f32x4){0.f, 0.f, 0.f, 0.f};

  const bf16_t* kbase = kt + (size_t)bh * LSEQ * HD;
  const bf16_t* vbase = vt + (size_t)bh * HD * LSEQ;
  const unsigned char* mrow = mask + (size_t)b * LSEQ;

  const int srow8 = lane >> 3;  // 0..7 within 8-row chunk
  const int scb   = lane & 7;   // LDS col-block position

  // prologue: stage tile 0 into buffer 0 (K rows sigma-permuted)
#pragma unroll
  for (int tt = 0; tt < 2; ++tt) {
    const int c = wave * 2 + tt;          // chunk 0..7 (8 rows each)
    const int p = c * 8 + srow8;          // LDS row (K: position, V: d)
    const int gcb = scb ^ (p & 7);        // XOR swizzle
    const int sig = ((p >> 5) << 5) | (((p >> 2) & 3) << 3) | (((p >> 4) & 1) << 2) | (p & 3);
    GLD16(kbase + (size_t)sig * HD + gcb * 8, &Kl[0][0] + c * 512);
    GLD16(vbase + (size_t)p * LSEQ + gcb * 8, &Vl[0][0] + c * 512);
  }
  __syncthreads();

  int cur = 0;
  for (int t = 0; t < 32; ++t) {
    const int k0 = t * 64;

    // prefetch next tile into the other buffer (hidden under this tile's work)
    if (t < 31) {
      const int k0n = k0 + 64;
      bf16_t* Kd = &Kl[cur ^ 1][0];
      bf16_t* Vd = &Vl[cur ^ 1][0];
#pragma unroll
      for (int tt = 0; tt < 2; ++tt) {
        const int c = wave * 2 + tt;
        const int p = c * 8 + srow8;
        const int gcb = scb ^ (p & 7);
        const int sig = ((p >> 5) << 5) | (((p >> 2) & 3) << 3) | (((p >> 4) & 1) << 2) | (p & 3);
        GLD16(kbase + (size_t)(k0n + sig) * HD + gcb * 8, Kd + c * 512);
        GLD16(vbase + (size_t)p * LSEQ + k0n + gcb * 8, Vd + c * 512);
      }
    }

    const bf16_t* Kc = &Kl[cur][0];
    const bf16_t* Vc = &Vl[cur][0];

    // mask bytes for this lane's sigma-positions: orig k = {quad*8..+7, 32+quad*8..+7}
    const uint64_t mlo = *(const uint64_t*)(mrow + k0 + quad * 8);
    const uint64_t mhi = *(const uint64_t*)(mrow + k0 + 32 + quad * 8);

    // S = exp2(scale*log2e * K.Q^T), swapped operands
    f32x4 S[2][4];
#pragma unroll
    for (int j = 0; j < 4; ++j) {
      const int row = j * 16 + l16;   // LDS position row
      const int sw  = row & 7;
      const bf16x8 kb0 = *(const bf16x8*)(Kc + row * 64 + ((quad)     ^ sw) * 8);
      const bf16x8 kb1 = *(const bf16x8*)(Kc + row * 64 + ((quad + 4) ^ sw) * 8);
#pragma unroll
      for (int u = 0; u < 2; ++u) {
        f32x4 a = (f32x4){0.f, 0.f, 0.f, 0.f};
        a = mfma_16x16x32(kb0, qa[u][0], a);
        a = mfma_16x16x32(kb1, qa[u][1], a);
#pragma unroll
        for (int r = 0; r < 4; ++r)
          S[u][j][r] = __builtin_amdgcn_exp2f(a[r] * scale_l2e);
      }
    }

    // masked positions -> P = 0 (uniform-branch slow path; fast path ~free)
    if (!__all((mlo | mhi) == 0)) {
#pragma unroll
      for (int j = 0; j < 4; ++j) {
        const uint64_t mm = (j & 2) ? mhi : mlo;
#pragma unroll
        for (int r = 0; r < 4; ++r)
          if ((mm >> (((j & 1) * 4 + r) * 8)) & 0xff) {
            S[0][j][r] = 0.f;
            S[1][j][r] = 0.f;
          }
      }
    }

    // l partials + in-register P transpose: slot s=f*32+quad*8+e holds orig k=s
    bf16x8 pa[2][2];
#pragma unroll
    for (int u = 0; u < 2; ++u) {
      float s = 0.f;
#pragma unroll
      for (int j = 0; j < 4; ++j)
        s += (S[u][j][0] + S[u][j][1]) + (S[u][j][2] + S[u][j][3]);
      l_part[u] += s;
#pragma unroll
      for (int f = 0; f < 2; ++f)
#pragma unroll
        for (int e = 0; e < 8; ++e)
          pa[u][f][e] = (bf16_t)S[u][2 * f + (e >> 2)][e & 3];
    }

    // O += P * V  (B-operand from Vl [d][kk], swizzled); V frags reused for both u
#pragma unroll
    for (int jd = 0; jd < 4; ++jd) {
      const int vrow = jd * 16 + l16;   // d-local
      const int sw   = vrow & 7;
      const bf16x8 vb0 = *(const bf16x8*)(Vc + vrow * 64 + ((quad)     ^ sw) * 8);
      const bf16x8 vb1 = *(const bf16x8*)(Vc + vrow * 64 + ((quad + 4) ^ sw) * 8);
#pragma unroll
      for (int u = 0; u < 2; ++u) {
        O[u][jd] = mfma_16x16x32(pa[u][0], vb0, O[u][jd]);
        O[u][jd] = mfma_16x16x32(pa[u][1], vb1, O[u][jd]);
      }
    }

    // one barrier per tile: waves done reading buf[cur] AND (implicit
    // vmcnt(0)+lgkmcnt(0) drain) next-tile prefetch landed in buf[cur^1]
    if (t < 31) __syncthreads();
    cur ^= 1;
  }

  // l reduction: sum across quads (each lane holds the 16 positions with
  // bits[3:2]==quad for q=l16), then redistribute to C-layout rows q=quad*4+r
  float linv[2][4];
#pragma unroll
  for (int u = 0; u < 2; ++u) {
    float s = l_part[u];
    s += __shfl_xor(s, 16);
    s += __shfl_xor(s, 32);            // every lane: total l for q = l16
#pragma unroll
    for (int r = 0; r < 4; ++r)
      linv[u][r] = 1.0f / __shfl(s, quad * 4 + r);
  }

  // epilogue: normalize and write ctx [B, LSEQ, NH*HD] bf16 (token-major)
#pragma unroll
  for (int u = 0; u < 2; ++u)
#pragma unroll
    for (int jd = 0; jd < 4; ++jd)
#pragma unroll
      for (int r = 0; r < 4; ++r) {
        const int l = q0 + wave * 32 + u * 16 + quad * 4 + r;
        const int d = h * HD + jd * 16 + l16;
        const float o = O[u][jd][r] * linv[u][r];
        ctx[((size_t)b * LSEQ + l) * DM + d] = (bf16_t)o;
      }
}

// ---------------------------------------------------------------------------
extern "C" void kernel_launch(void* const* d_in, const int* in_sizes, int n_in,
                              void* d_out, int out_size, void* d_ws, size_t ws_size,
                              hipStream_t stream) {
  (void)in_sizes; (void)n_in; (void)out_size; (void)ws_size;
  const float* query = (const float*)d_in[0];
  const float* key   = (const float*)d_in[1];
  const float* value = (const float*)d_in[2];
  const float* cos_q = (const float*)d_in[3];
  const float* sin_q = (const float*)d_in[4];
  const float* cos_k = (const float*)d_in[5];
  const float* sin_k = (const float*)d_in[6];
  const unsigned char* mask = (const unsigned char*)d_in[7];
  const float* Wq = (const float*)d_in[8];
  const float* bq = (const float*)d_in[9];
  const float* Wk = (const float*)d_in[10];
  const float* bk = (const float*)d_in[11];
  const float* Wv = (const float*)d_in[12];
  const float* bv = (const float*)d_in[13];
  const float* Wo = (const float*)d_in[14];
  const float* bo = (const float*)d_in[15];
  float* out = (float*)d_out;

  const size_t ACT = (size_t)TOKENS * DM;  // 8388608
  const size_t WEL = (size_t)DM * DM;      // 1048576

  bf16_t* p   = (bf16_t*)d_ws;
  bf16_t* xq  = p; p += ACT;    // xq,xk,xv contiguous (cast3 dst / qkv A base)
  bf16_t* xk  = p; p += ACT;
  bf16_t* xv  = p; p += ACT;
  bf16_t* wqb = p; p += WEL;    // wqb..wob contiguous (cast4 dst / qkv W base)
  bf16_t* wkb = p; p += WEL;
  bf16_t* wvb = p; p += WEL;
  bf16_t* wob = p; p += WEL;
  bf16_t* qtb = p; p += ACT;
  bf16_t* ktb = p; p += ACT;
  bf16_t* vtb = p; p += ACT;
  bf16_t* ctx = xk;  // alias: xk dead after qkv proj
  (void)xv; (void)wkb; (void)wvb;

  // casts (f32 -> bf16): 2 dispatches
  cast3_kernel<<<dim3((int)(ACT / 1024), 3), 256, 0, stream>>>(query, key, value, xq, (int)ACT);
  cast4_kernel<<<dim3((int)(WEL / 1024), 4), 256, 0, stream>>>(Wq, Wk, Wv, Wo, wqb, (int)WEL);

  // fused q/k/v projections (one dispatch, z = which projection)
  qkv_proj_kernel<<<dim3(TOKENS / 128, DM / 128, 3), 256, 0, stream>>>(
      xq, wqb, bq, bk, bv, cos_q, sin_q, cos_k, sin_k, qtb, ktb, vtb);

  // flash attention -> ctx [B, LSEQ, DM] bf16
  attn_kernel<<<dim3(LSEQ / 128, B_DIM * NH), 256, 0, stream>>>(qtb, ktb, vtb, mask, ctx);

  // output projection -> f32 d_out
  out_gemm_kernel<<<dim3(TOKENS / 128, DM / 128), 256, 0, stream>>>(ctx, wob, bo, out);
}

// Round 2
// 365.744 us; speedup vs baseline: 1.0734x; 1.0103x over previous
//
#include <hip/hip_runtime.h>
#include <hip/hip_bf16.h>
#include <stdint.h>
#include <stddef.h>

// Problem constants (fixed by the reference)
#define B_DIM 4
#define NH    16
#define LSEQ  2048
#define HD    64
#define DM    1024
#define TOKENS (B_DIM * LSEQ)   // 8192

typedef __bf16 bf16_t;
typedef __attribute__((ext_vector_type(8))) __bf16 bf16x8;
typedef __attribute__((ext_vector_type(4))) __bf16 bf16x4;
typedef __attribute__((ext_vector_type(4))) float  f32x4;

// async global->LDS, 16B per lane, lane i lands at ldsbase + i*16
#define GLD16(gp, lp) \
  __builtin_amdgcn_global_load_lds((__attribute__((address_space(1))) void*)(gp), \
                                   (__attribute__((address_space(3))) void*)(lp), 16, 0, 0)

__device__ __forceinline__ f32x4 mfma_16x16x32(bf16x8 a, bf16x8 b, f32x4 c) {
  return __builtin_amdgcn_mfma_f32_16x16x32_bf16(a, b, c, 0, 0, 0);
}

// ---------------------------------------------------------------------------
// Casts: 3 activations (dst contiguous: xq,xk,xv) / 4 weights (wq,wk,wv,wo)
// ---------------------------------------------------------------------------
__global__ __launch_bounds__(256) void cast3_kernel(const float* __restrict__ a,
                                                    const float* __restrict__ b,
                                                    const float* __restrict__ c,
                                                    bf16_t* __restrict__ dst, int n) {
  const float* src = (blockIdx.y == 0) ? a : (blockIdx.y == 1) ? b : c;
  const int i = (blockIdx.x * 256 + threadIdx.x) * 4;
  if (i < n) {
    const float4 v = *(const float4*)(src + i);
    bf16x4 o;
    o[0] = (bf16_t)v.x; o[1] = (bf16_t)v.y; o[2] = (bf16_t)v.z; o[3] = (bf16_t)v.w;
    *(bf16x4*)(dst + (size_t)blockIdx.y * n + i) = o;
  }
}

__global__ __launch_bounds__(256) void cast4_kernel(const float* __restrict__ a,
                                                    const float* __restrict__ b,
                                                    const float* __restrict__ c,
                                                    const float* __restrict__ d,
                                                    bf16_t* __restrict__ dst, int n) {
  const float* src = (blockIdx.y == 0) ? a : (blockIdx.y == 1) ? b
                   : (blockIdx.y == 2) ? c : d;
  const int i = (blockIdx.x * 256 + threadIdx.x) * 4;
  if (i < n) {
    const float4 v = *(const float4*)(src + i);
    bf16x4 o;
    o[0] = (bf16_t)v.x; o[1] = (bf16_t)v.y; o[2] = (bf16_t)v.z; o[3] = (bf16_t)v.w;
    *(bf16x4*)(dst + (size_t)blockIdx.y * n + i) = o;
  }
}

// ---------------------------------------------------------------------------
// Fused QKV projection: ONE dispatch, blockIdx.z in {0,1,2} = q,k,v.
// 128x128-tile bf16 GEMM (m97 structure): C = X_z * W_z^T + bias_z, then:
//   z<2 : RoPE epilogue -> head-split [B,NH,LSEQ,HD]
//   z==2: transposed store -> [B,NH,HD,LSEQ] (PV B-operand contiguity)
// ---------------------------------------------------------------------------
__global__ __launch_bounds__(256) void qkv_proj_kernel(const bf16_t* __restrict__ X,
                                                       const bf16_t* __restrict__ Wb,
                                                       const float* __restrict__ bq,
                                                       const float* __restrict__ bk,
                                                       const float* __restrict__ bv,
                                                       const float* __restrict__ cos_q,
                                                       const float* __restrict__ sin_q,
                                                       const float* __restrict__ cos_k,
                                                       const float* __restrict__ sin_k,
                                                       bf16_t* __restrict__ qtb,
                                                       bf16_t* __restrict__ ktb,
                                                       bf16_t* __restrict__ vtb) {
  __shared__ bf16_t As[128 * 32];
  __shared__ bf16_t Bs[128 * 32];
  const int z = blockIdx.z;
  const bf16_t* A  = X  + (size_t)z * TOKENS * DM;
  const bf16_t* Bw = Wb + (size_t)z * DM * DM;
  const float* bias = (z == 0) ? bq : (z == 1) ? bk : bv;

  const int tid  = threadIdx.x;
  const int wave = tid >> 6, lane = tid & 63;
  const int quad = lane >> 4, l16 = lane & 15;
  const int m0 = blockIdx.x * 128, n0 = blockIdx.y * 128;
  const int wm = (wave >> 1) * 64, wn = (wave & 1) * 64;

  f32x4 acc[4][4];
#pragma unroll
  for (int i = 0; i < 4; ++i)
#pragma unroll
    for (int j = 0; j < 4; ++j) acc[i][j] = (f32x4){0.f, 0.f, 0.f, 0.f};

  const int srow = lane >> 2;        // 0..15 (row within 16-row chunk)
  const int scol = (lane & 3) * 8;   // 0,8,16,24

  for (int kk = 0; kk < DM; kk += 32) {
    __syncthreads();
#pragma unroll
    for (int t = 0; t < 2; ++t) {
      const int c   = wave * 2 + t;        // chunk 0..7, 16 rows each
      const int row = c * 16 + srow;
      GLD16(A  + (size_t)(m0 + row) * DM + kk + scol, As + c * 512);
      GLD16(Bw + (size_t)(n0 + row) * DM + kk + scol, Bs + c * 512);
    }
    __syncthreads();
    bf16x8 af[4], bfr[4];
#pragma unroll
    for (int i = 0; i < 4; ++i)
      af[i] = *(const bf16x8*)(As + (wm + i * 16 + l16) * 32 + quad * 8);
#pragma unroll
    for (int j = 0; j < 4; ++j)
      bfr[j] = *(const bf16x8*)(Bs + (wn + j * 16 + l16) * 32 + quad * 8);
#pragma unroll
    for (int i = 0; i < 4; ++i)
#pragma unroll
      for (int j = 0; j < 4; ++j)
        acc[i][j] = mfma_16x16x32(af[i], bfr[j], acc[i][j]);
  }

  // epilogue: C row = quad*4+reg, col = l16 (m89-verified C/D layout)
  if (z < 2) {
    const float* cosb = (z == 0) ? cos_q : cos_k;
    const float* sinb = (z == 0) ? sin_q : sin_k;
    bf16_t* out = (z == 0) ? qtb : ktb;
    const int h = (n0 + wn) >> 6;
#pragma unroll
    for (int i = 0; i < 4; ++i) {
#pragma unroll
      for (int j = 0; j < 2; ++j) {
        const int hd1 = j * 16 + l16;
        const int hd2 = hd1 + 32;
        const float bn1 = bias[n0 + wn + hd1];
        const float bn2 = bias[n0 + wn + hd2];
#pragma unroll
        for (int r = 0; r < 4; ++r) {
          const int m = m0 + wm + i * 16 + quad * 4 + r;
          const int b = m >> 11, l = m & (LSEQ - 1);
          const size_t cb = ((size_t)b * LSEQ + l) * HD;
          const float x1 = (float)(bf16_t)(acc[i][j][r] + bn1);
          const float x2 = (float)(bf16_t)(acc[i][j + 2][r] + bn2);
          const float c1 = cosb[cb + hd1], s1 = sinb[cb + hd1];
          const float c2 = cosb[cb + hd2], s2 = sinb[cb + hd2];
          bf16_t* dst = out + (((size_t)(b * NH + h)) * LSEQ + l) * HD;
          dst[hd1] = (bf16_t)(x1 * c1 - x2 * s1);
          dst[hd2] = (bf16_t)(x2 * c2 + x1 * s2);
        }
      }
    }
  } else {
#pragma unroll
    for (int i = 0; i < 4; ++i) {
      const int mb = m0 + wm + i * 16 + quad * 4;
      const int b = mb >> 11, l = mb & (LSEQ - 1);
#pragma unroll
      for (int j = 0; j < 4; ++j) {
        const int n = n0 + wn + j * 16 + l16;
        const int h = n >> 6, hd = n & (HD - 1);
        const float bn = bias[n];
        bf16x4 pk;
#pragma unroll
        for (int r = 0; r < 4; ++r) pk[r] = (bf16_t)(acc[i][j][r] + bn);
        *(bf16x4*)(vtb + (((size_t)(b * NH + h)) * HD + hd) * LSEQ + l) = pk;
      }
    }
  }
}

// ---------------------------------------------------------------------------
// Out projection: C = A * Wo^T + bo, f32 store (m97 structure)
// ---------------------------------------------------------------------------
__global__ __launch_bounds__(256) void out_gemm_kernel(const bf16_t* __restrict__ A,
                                                       const bf16_t* __restrict__ Bw,
                                                       const float* __restrict__ bias,
                                                       float* __restrict__ out) {
  __shared__ bf16_t As[128 * 32];
  __shared__ bf16_t Bs[128 * 32];
  const int tid  = threadIdx.x;
  const int wave = tid >> 6, lane = tid & 63;
  const int quad = lane >> 4, l16 = lane & 15;
  const int m0 = blockIdx.x * 128, n0 = blockIdx.y * 128;
  const int wm = (wave >> 1) * 64, wn = (wave & 1) * 64;

  f32x4 acc[4][4];
#pragma unroll
  for (int i = 0; i < 4; ++i)
#pragma unroll
    for (int j = 0; j < 4; ++j) acc[i][j] = (f32x4){0.f, 0.f, 0.f, 0.f};

  const int srow = lane >> 2;
  const int scol = (lane & 3) * 8;

  for (int kk = 0; kk < DM; kk += 32) {
    __syncthreads();
#pragma unroll
    for (int t = 0; t < 2; ++t) {
      const int c   = wave * 2 + t;
      const int row = c * 16 + srow;
      GLD16(A  + (size_t)(m0 + row) * DM + kk + scol, As + c * 512);
      GLD16(Bw + (size_t)(n0 + row) * DM + kk + scol, Bs + c * 512);
    }
    __syncthreads();
    bf16x8 af[4], bfr[4];
#pragma unroll
    for (int i = 0; i < 4; ++i)
      af[i] = *(const bf16x8*)(As + (wm + i * 16 + l16) * 32 + quad * 8);
#pragma unroll
    for (int j = 0; j < 4; ++j)
      bfr[j] = *(const bf16x8*)(Bs + (wn + j * 16 + l16) * 32 + quad * 8);
#pragma unroll
    for (int i = 0; i < 4; ++i)
#pragma unroll
      for (int j = 0; j < 4; ++j)
        acc[i][j] = mfma_16x16x32(af[i], bfr[j], acc[i][j]);
  }

#pragma unroll
  for (int i = 0; i < 4; ++i)
#pragma unroll
    for (int j = 0; j < 4; ++j) {
      const int n  = n0 + wn + j * 16 + l16;
      const float bn = bias[n];
#pragma unroll
      for (int r = 0; r < 4; ++r) {
        const int m = m0 + wm + i * 16 + quad * 4 + r;
        out[(size_t)m * DM + n] = acc[i][j][r] + bn;
      }
    }
}

// ---------------------------------------------------------------------------
// Flash attention v6: grid (LSEQ/128, B*NH), 256 threads (4 waves x 32 q-rows).
// Round-6 (cycle accounting from v5 counters: makespan ~7.2Kcy/SIMD/tile,
// VALU-busy 55% is the dominant pipe; true MFMA work only ~9%; prefetch
// latency already hidden -> deeper buffering useless; cut VALU instead):
//  - mask pre-scan: 256 threads x 8B cover the 2048B row once; LDS-atomic OR
//    flag. All-false mask (the bench case) -> in-loop mask path is one
//    wave-uniform execz skip. Removes 2 VMEM + ~25 VALU per tile.
//  - l via ones-MFMA: O_l[u] = mfma(pa[u][k], ones) accumulates row sums of P
//    on the (91% idle) matrix pipe; every lane gets l(q) for its C-layout row
//    q=quad*4+r directly -> epilogue linv = 1/O_l[u][r], NO shfl reduce.
//    Replaces ~26 serial-chain VALU adds/tile with 4 MFMA. (l now sums the
//    bf16-rounded P -- self-consistent with O = sum P_bf16 * V.)
//  - hoisted addressing: sw = l16&7 is j-invariant, so K/V fragment reads are
//    2 per-lane base offsets + compile-time offset: immediates (j*2KB);
//    staging global/LDS offsets precomputed per lane, +k0*stride per tile.
//  - keeps v5's verified sigma-permuted K staging, in-register P transpose,
//    XOR swizzle, 2-deep buffer, one barrier per tile.
// ---------------------------------------------------------------------------
__global__ __launch_bounds__(256, 4) void attn_kernel(const bf16_t* __restrict__ qt,
                                                      const bf16_t* __restrict__ kt,
                                                      const bf16_t* __restrict__ vt,
                                                      const unsigned char* __restrict__ mask,
                                                      bf16_t* __restrict__ ctx) {
  __shared__ bf16_t Kl[2][64 * 64];        // [pos][d], col-blocks swizzled by pos&7
  __shared__ bf16_t Vl[2][64 * 64];        // [d][kk],  col-blocks swizzled by d&7
  __shared__ int mflag;
  const int bh = blockIdx.y;
  const int b = bh >> 4, h = bh & (NH - 1);
  const int q0 = blockIdx.x * 128;
  const int tid = threadIdx.x;
  const int wave = tid >> 6, lane = tid & 63;
  const int quad = lane >> 4, l16 = lane & 15;
  const float scale_l2e = 0.125f * 1.44269504f;  // HD^-0.5 * log2(e)

  const bf16_t* kbase = kt + (size_t)bh * LSEQ * HD;
  const bf16_t* vbase = vt + (size_t)bh * HD * LSEQ;
  const unsigned char* mrow = mask + (size_t)b * LSEQ;

  if (tid == 0) mflag = 0;
  __syncthreads();
  // mask pre-scan: 256 threads x 8B = entire 2048B row
  {
    const uint64_t mw = ((const uint64_t*)mrow)[tid];
    if (mw != 0) atomicOr(&mflag, 1);
  }

  // Q fragments (m=l16, k=quad*8+e), used as B-operand of swapped QK^T
  bf16x8 qa[2][2];
#pragma unroll
  for (int u = 0; u < 2; ++u) {
    const bf16_t* qrow = qt + (((size_t)bh * LSEQ) + q0 + wave * 32 + u * 16 + l16) * HD;
    qa[u][0] = *(const bf16x8*)(qrow + quad * 8);
    qa[u][1] = *(const bf16x8*)(qrow + 32 + quad * 8);
  }

  f32x4 O[2][4];
  f32x4 Ol[2];
#pragma unroll
  for (int u = 0; u < 2; ++u) {
    Ol[u] = (f32x4){0.f, 0.f, 0.f, 0.f};
#pragma unroll
    for (int j = 0; j < 4; ++j) O[u][j] = (f32x4){0.f, 0.f, 0.f, 0.f};
  }
  bf16x8 ones;
#pragma unroll
  for (int e = 0; e < 8; ++e) ones[e] = (bf16_t)1.0f;

  // --- hoisted per-lane offsets ---
  const int srow8 = lane >> 3;  // 0..7 within 8-row chunk
  const int scb   = lane & 7;   // LDS col-block position
  const int c0 = wave * 2, c1 = c0 + 1;
  const int p0 = c0 * 8 + srow8, p1 = p0 + 8;
  const int g0 = (scb ^ srow8) * 8;   // p&7 == srow8 for both chunks
  const int sig0 = ((p0 >> 5) << 5) | (((p0 >> 2) & 3) << 3) | (((p0 >> 4) & 1) << 2) | (p0 & 3);
  const int sig1 = ((p1 >> 5) << 5) | (((p1 >> 2) & 3) << 3) | (((p1 >> 4) & 1) << 2) | (p1 & 3);
  const int kgo0 = sig0 * HD + g0, kgo1 = sig1 * HD + g0;      // K global lane offsets
  const int vgo0 = p0 * LSEQ + g0, vgo1 = p1 * LSEQ + g0;      // V global lane offsets
  const int ld0 = c0 * 512, ld1 = c1 * 512;                    // LDS dst offsets

  // fragment-read offsets: sw = (j*16+l16)&7 == l16&7 for all j
  const int sw  = l16 & 7;
  const int oA  = l16 * 64 + ((quad ^ sw) << 3);
  const int oB  = l16 * 64 + (((quad + 4) ^ sw) << 3);

  // prologue: stage tile 0 into buffer 0 (K rows sigma-permuted)
  GLD16(kbase + kgo0, &Kl[0][0] + ld0);
  GLD16(kbase + kgo1, &Kl[0][0] + ld1);
  GLD16(vbase + vgo0, &Vl[0][0] + ld0);
  GLD16(vbase + vgo1, &Vl[0][0] + ld1);
  __syncthreads();
  const bool has_mask = (mflag != 0);

  int cur = 0;
  for (int t = 0; t < 32; ++t) {
    const int k0 = t * 64;

    // prefetch next tile into the other buffer (hidden under this tile's work)
    if (t < 31) {
      const int k0n = k0 + 64;
      bf16_t* Kd = &Kl[cur ^ 1][0];
      bf16_t* Vd = &Vl[cur ^ 1][0];
      GLD16(kbase + (size_t)k0n * HD + kgo0, Kd + ld0);
      GLD16(kbase + (size_t)k0n * HD + kgo1, Kd + ld1);
      GLD16(vbase + (size_t)(vgo0 + k0n), Vd + ld0);
      GLD16(vbase + (size_t)(vgo1 + k0n), Vd + ld1);
    }

    const bf16_t* Kc = &Kl[cur][0];
    const bf16_t* Vc = &Vl[cur][0];

    // S = exp2(scale*log2e * K.Q^T), swapped operands
    f32x4 S[2][4];
#pragma unroll
    for (int j = 0; j < 4; ++j) {
      const bf16x8 kb0 = *(const bf16x8*)(Kc + oA + j * 1024);
      const bf16x8 kb1 = *(const bf16x8*)(Kc + oB + j * 1024);
#pragma unroll
      for (int u = 0; u < 2; ++u) {
        f32x4 a = (f32x4){0.f, 0.f, 0.f, 0.f};
        a = mfma_16x16x32(kb0, qa[u][0], a);
        a = mfma_16x16x32(kb1, qa[u][1], a);
#pragma unroll
        for (int r = 0; r < 4; ++r)
          S[u][j][r] = __builtin_amdgcn_exp2f(a[r] * scale_l2e);
      }
    }

    // masked positions -> P = 0 (block-uniform skip when mask all-false)
    if (has_mask) {
      const uint64_t mlo = *(const uint64_t*)(mrow + k0 + quad * 8);
      const uint64_t mhi = *(const uint64_t*)(mrow + k0 + 32 + quad * 8);
      if (!__all((mlo | mhi) == 0)) {
#pragma unroll
        for (int j = 0; j < 4; ++j) {
          const uint64_t mm = (j & 2) ? mhi : mlo;
#pragma unroll
          for (int r = 0; r < 4; ++r)
            if ((mm >> (((j & 1) * 4 + r) * 8)) & 0xff) {
              S[0][j][r] = 0.f;
              S[1][j][r] = 0.f;
            }
        }
      }
    }

    // in-register P transpose: slot s=f*32+quad*8+e holds orig k=s
    bf16x8 pa[2][2];
#pragma unroll
    for (int u = 0; u < 2; ++u)
#pragma unroll
      for (int f = 0; f < 2; ++f)
#pragma unroll
        for (int e = 0; e < 8; ++e)
          pa[u][f][e] = (bf16_t)S[u][2 * f + (e >> 2)][e & 3];

    // l via ones-MFMA: every lane accumulates l(q) for q=quad*4+r in Ol[u][r]
#pragma unroll
    for (int u = 0; u < 2; ++u) {
      Ol[u] = mfma_16x16x32(pa[u][0], ones, Ol[u]);
      Ol[u] = mfma_16x16x32(pa[u][1], ones, Ol[u]);
    }

    // O += P * V  (B-operand from Vl [d][kk], swizzled); V frags reused for both u
#pragma unroll
    for (int jd = 0; jd < 4; ++jd) {
      const bf16x8 vb0 = *(const bf16x8*)(Vc + oA + jd * 1024);
      const bf16x8 vb1 = *(const bf16x8*)(Vc + oB + jd * 1024);
#pragma unroll
      for (int u = 0; u < 2; ++u) {
        O[u][jd] = mfma_16x16x32(pa[u][0], vb0, O[u][jd]);
        O[u][jd] = mfma_16x16x32(pa[u][1], vb1, O[u][jd]);
      }
    }

    // one barrier per tile: waves done reading buf[cur] AND (implicit
    // vmcnt(0)+lgkmcnt(0) drain) next-tile prefetch landed in buf[cur^1]
    if (t < 31) __syncthreads();
    cur ^= 1;
  }

  // epilogue: normalize and write ctx [B, LSEQ, NH*HD] bf16 (token-major)
#pragma unroll
  for (int u = 0; u < 2; ++u) {
    f32x4 linv;
#pragma unroll
    for (int r = 0; r < 4; ++r) linv[r] = 1.0f / Ol[u][r];
#pragma unroll
    for (int jd = 0; jd < 4; ++jd)
#pragma unroll
      for (int r = 0; r < 4; ++r) {
        const int l = q0 + wave * 32 + u * 16 + quad * 4 + r;
        const int d = h * HD + jd * 16 + l16;
        const float o = O[u][jd][r] * linv[r];
        ctx[((size_t)b * LSEQ + l) * DM + d] = (bf16_t)o;
      }
  }
}

// ---------------------------------------------------------------------------
extern "C" void kernel_launch(void* const* d_in, const int* in_sizes, int n_in,
                              void* d_out, int out_size, void* d_ws, size_t ws_size,
                              hipStream_t stream) {
  (void)in_sizes; (void)n_in; (void)out_size; (void)ws_size;
  const float* query = (const float*)d_in[0];
  const float* key   = (const float*)d_in[1];
  const float* value = (const float*)d_in[2];
  const float* cos_q = (const float*)d_in[3];
  const float* sin_q = (const float*)d_in[4];
  const float* cos_k = (const float*)d_in[5];
  const float* sin_k = (const float*)d_in[6];
  const unsigned char* mask = (const unsigned char*)d_in[7];
  const float* Wq = (const float*)d_in[8];
  const float* bq = (const float*)d_in[9];
  const float* Wk = (const float*)d_in[10];
  const float* bk = (const float*)d_in[11];
  const float* Wv = (const float*)d_in[12];
  const float* bv = (const float*)d_in[13];
  const float* Wo = (const float*)d_in[14];
  const float* bo = (const float*)d_in[15];
  float* out = (float*)d_out;

  const size_t ACT = (size_t)TOKENS * DM;  // 8388608
  const size_t WEL = (size_t)DM * DM;      // 1048576

  bf16_t* p   = (bf16_t*)d_ws;
  bf16_t* xq  = p; p += ACT;    // xq,xk,xv contiguous (cast3 dst / qkv A base)
  bf16_t* xk  = p; p += ACT;
  bf16_t* xv  = p; p += ACT;
  bf16_t* wqb = p; p += WEL;    // wqb..wob contiguous (cast4 dst / qkv W base)
  bf16_t* wkb = p; p += WEL;
  bf16_t* wvb = p; p += WEL;
  bf16_t* wob = p; p += WEL;
  bf16_t* qtb = p; p += ACT;
  bf16_t* ktb = p; p += ACT;
  bf16_t* vtb = p; p += ACT;
  bf16_t* ctx = xk;  // alias: xk dead after qkv proj
  (void)xv; (void)wkb; (void)wvb;

  // casts (f32 -> bf16): 2 dispatches
  cast3_kernel<<<dim3((int)(ACT / 1024), 3), 256, 0, stream>>>(query, key, value, xq, (int)ACT);
  cast4_kernel<<<dim3((int)(WEL / 1024), 4), 256, 0, stream>>>(Wq, Wk, Wv, Wo, wqb, (int)WEL);

  // fused q/k/v projections (one dispatch, z = which projection)
  qkv_proj_kernel<<<dim3(TOKENS / 128, DM / 128, 3), 256, 0, stream>>>(
      xq, wqb, bq, bk, bv, cos_q, sin_q, cos_k, sin_k, qtb, ktb, vtb);

  // flash attention -> ctx [B, LSEQ, DM] bf16
  attn_kernel<<<dim3(LSEQ / 128, B_DIM * NH), 256, 0, stream>>>(qtb, ktb, vtb, mask, ctx);

  // output projection -> f32 d_out
  out_gemm_kernel<<<dim3(TOKENS / 128, DM / 128), 256, 0, stream>>>(ctx, wob, bo, out);
}